// Round 4
// baseline (190.048 us; speedup 1.0000x reference)
//
#include <hip/hip_runtime.h>
#include <hip/hip_bf16.h>

// Problem: T=255, B=256, NIN=784, NOUT=40
// out layout: [spk_rec (255*256*40) | mem_rec (255*256*40)] fp32
#define T_STEPS 255
#define BATCH 256
#define NIN 784
#define NOUT 40
#define MROWS (T_STEPS * BATCH)          // 65280
#define TBN (T_STEPS * BATCH * NOUT)     // 2611200
#define BN_CH (BATCH * NOUT)             // 10240

#define BM 64     // rows per block -> grid 1020 -> ~4 blocks/CU (was 510/2)
#define BK 56     // 784 = 14 * 56
#define LDX 60    // padded LDS row stride (dwords); conflict-free b128 reads

// Convert W to fp64 once. Wd lives at the head of the spk output region
// (251 KB << 10.4 MB); the scan kernel overwrites that region afterwards.
__global__ __launch_bounds__(256) void wconv_kernel(
    const float* __restrict__ W, double* __restrict__ Wd) {
  int i = blockIdx.x * 256 + threadIdx.x;
  if (i < NOUT * NIN) Wd[i] = (double)W[i];
}

__global__ __launch_bounds__(256) void lif_gemm_kernel(
    const float* __restrict__ X, const double* __restrict__ Wd,
    float* __restrict__ cur) {
  __shared__ float xs[BM * LDX];
  const int tid = threadIdx.x;
  const int m0 = blockIdx.x * BM;
  const int tm = tid & 63;  // row (one per thread)
  // wave-uniform output-column base -> Wd reads scalarize to s_load
  const int nbu = __builtin_amdgcn_readfirstlane((int)(threadIdx.x >> 6)) * 10;

  // fp64 accumulation, FMA order per output element bit-identical to the
  // validated round-2/3 kernels (k ascending, quads of 4 sequential FMAs):
  // cur must be correctly-rounded fp32 so threshold decisions match refs.
  double acc[10];
#pragma unroll
  for (int j = 0; j < 10; ++j) acc[j] = 0.0;

  for (int k0 = 0; k0 < NIN; k0 += BK) {
    // stage X tile: 64 rows x 56 cols = 896 float4 over 256 threads
#pragma unroll
    for (int i = 0; i < 4; ++i) {
      unsigned id = tid + i * 256u;
      if (id < BM * 14u) {
        unsigned row = id / 14u;  // 14 float4 per row
        unsigned c4 = id % 14u;
        float4 v = *reinterpret_cast<const float4*>(
            X + (size_t)(m0 + row) * NIN + k0 + c4 * 4);
        *reinterpret_cast<float4*>(&xs[row * LDX + c4 * 4]) = v;
      }
    }
    __syncthreads();

#pragma unroll
    for (int kk = 0; kk < BK; kk += 4) {
      float4 xv = *reinterpret_cast<const float4*>(&xs[tm * LDX + kk]);
      double xa = (double)xv.x, xb = (double)xv.y,
             xc = (double)xv.z, xd = (double)xv.w;
      const double* wbase = Wd + (size_t)nbu * NIN + k0 + kk;
#pragma unroll
      for (int j = 0; j < 10; ++j) {
        const double* wr = wbase + (size_t)j * NIN;
        double wa = wr[0], wb = wr[1], wc = wr[2], wd = wr[3];
        acc[j] = fma(xa, wa, acc[j]);
        acc[j] = fma(xb, wb, acc[j]);
        acc[j] = fma(xc, wc, acc[j]);
        acc[j] = fma(xd, wd, acc[j]);
      }
    }
    __syncthreads();
  }

  const size_t mrow = (size_t)m0 + tm;
#pragma unroll
  for (int j = 0; j < 10; ++j)
    cur[mrow * NOUT + nbu + j] = (float)acc[j];
}

// One thread per (b, n) chain; 17 chunks of 15 t-steps, next chunk's cur
// loads prefetched before computing the current chunk (hides L2 latency).
// Per-step math identical to the validated scan (asm barrier blocks fma
// contraction of 0.95f*mem + cur, matching numpy's two roundings).
__global__ __launch_bounds__(64) void lif_scan_kernel(
    float* __restrict__ spk, float* __restrict__ curmem) {
  const int idx = blockIdx.x * 64 + threadIdx.x;  // 0..10239
  float mem = 0.f;
  float c[15];
#pragma unroll
  for (int i = 0; i < 15; ++i) c[i] = curmem[(size_t)i * BN_CH + idx];

  for (int ch = 0; ch < 17; ++ch) {
    const int t0 = ch * 15;
    float n[15];
    if (ch != 16) {
#pragma unroll
      for (int i = 0; i < 15; ++i)
        n[i] = curmem[(size_t)(t0 + 15 + i) * BN_CH + idx];
    }
    float m_[15], s_[15];
#pragma unroll
    for (int i = 0; i < 15; ++i) {
      float reset = (mem > 1.0f) ? 1.0f : 0.0f;
      float decay = 0.95f * mem;
      asm volatile("" : "+v"(decay));  // forbid fma contraction
      float summ = decay + c[i];
      float mnew = summ * (1.0f - reset);
      m_[i] = mnew;
      s_[i] = (mnew > 1.0f) ? 1.0f : 0.0f;
      mem = mnew;
    }
#pragma unroll
    for (int i = 0; i < 15; ++i) {
      curmem[(size_t)(t0 + i) * BN_CH + idx] = m_[i];
      spk[(size_t)(t0 + i) * BN_CH + idx] = s_[i];
    }
    if (ch != 16) {
#pragma unroll
      for (int i = 0; i < 15; ++i) c[i] = n[i];
    }
  }
}

extern "C" void kernel_launch(void* const* d_in, const int* in_sizes, int n_in,
                              void* d_out, int out_size, void* d_ws,
                              size_t ws_size, hipStream_t stream) {
  (void)in_sizes; (void)n_in; (void)out_size; (void)d_ws; (void)ws_size;
  const float* X = (const float*)d_in[0];
  const float* W = (const float*)d_in[1];
  float* out = (float*)d_out;
  float* spk = out;            // [255,256,40]
  float* memout = out + TBN;   // [255,256,40], used as cur scratch then mem
  double* Wd = (double*)out;   // 251 KB scratch at head of spk region

  wconv_kernel<<<(NOUT * NIN + 255) / 256, 256, 0, stream>>>(W, Wd);
  lif_gemm_kernel<<<MROWS / BM, 256, 0, stream>>>(X, Wd, memout);
  lif_scan_kernel<<<BN_CH / 64, 64, 0, stream>>>(spk, memout);
}

// Round 5
// 158.523 us; speedup vs baseline: 1.1989x; 1.1989x over previous
//
#include <hip/hip_runtime.h>
#include <hip/hip_bf16.h>

// Problem: T=255, B=256, NIN=784, NOUT=40
// out layout: [spk_rec (255*256*40) | mem_rec (255*256*40)] fp32
#define T_STEPS 255
#define BATCH 256
#define NIN 784
#define NOUT 40
#define MROWS (T_STEPS * BATCH)          // 65280
#define TBN (T_STEPS * BATCH * NOUT)     // 2611200
#define BN_CH (BATCH * NOUT)             // 10240

#define BM 128    // rows per block (2 rows/thread) -> grid 510 -> 2 blocks/CU
#define BK 56     // 784 = 14 * 56
#define LDX 60    // padded LDS row stride (dwords); conflict-free b128 reads

// Convert W to fp64 once. Wd lives at the head of the spk output region
// (251 KB << 10.4 MB); the scan kernel overwrites that region afterwards.
__global__ __launch_bounds__(256) void wconv_kernel(
    const float* __restrict__ W, double* __restrict__ Wd) {
  int i = blockIdx.x * 256 + threadIdx.x;
  if (i < NOUT * NIN) Wd[i] = (double)W[i];
}

__global__ __launch_bounds__(256) void lif_gemm_kernel(
    const float* __restrict__ X, const double* __restrict__ Wd,
    float* __restrict__ cur) {
  __shared__ float xs[BM * LDX];          // 30.7 KB
  __shared__ double wlds[NOUT * BK];      // 17.9 KB, [40][56] fp64, broadcast
  const int tid = threadIdx.x;
  const int m0 = blockIdx.x * BM;
  const int tm = tid & 63;   // row within half-tile
  const int tn = tid >> 6;   // wave-uniform 0..3
  const int nbu = tn * 10;

  // fp64 accumulation, FMA chain per output element bit-identical to the
  // validated kernels (k ascending, quads of 4 sequential FMAs): cur must be
  // correctly-rounded fp32 so threshold decisions match the references.
  double acc[2][10];
#pragma unroll
  for (int r = 0; r < 2; ++r)
#pragma unroll
    for (int j = 0; j < 10; ++j) acc[r][j] = 0.0;

  for (int k0 = 0; k0 < NIN; k0 += BK) {
    // stage X tile: 128 rows x 56 cols = 1792 float4 / 256 threads = 7 each
#pragma unroll
    for (int i = 0; i < 7; ++i) {
      unsigned id = tid + i * 256u;
      unsigned row = id / 14u;  // 14 float4 per row
      unsigned c4 = id % 14u;
      float4 v = *reinterpret_cast<const float4*>(
          X + (size_t)(m0 + row) * NIN + k0 + c4 * 4);
      *reinterpret_cast<float4*>(&xs[row * LDX + c4 * 4]) = v;
    }
    // stage W tile: 40 rows x 56 cols fp64 = 1120 double2 over 256 threads
#pragma unroll
    for (int i = 0; i < 5; ++i) {
      unsigned id = tid + i * 256u;
      if (id < NOUT * (BK / 2)) {
        unsigned row = id / 28u;  // 28 double2 per row
        unsigned c2 = id % 28u;
        double2 v = *reinterpret_cast<const double2*>(
            Wd + (size_t)row * NIN + k0 + c2 * 2);
        *reinterpret_cast<double2*>(&wlds[row * BK + c2 * 2]) = v;
      }
    }
    __syncthreads();

#pragma unroll
    for (int kk = 0; kk < BK; kk += 4) {
      float4 xv0 = *reinterpret_cast<const float4*>(&xs[tm * LDX + kk]);
      float4 xv1 = *reinterpret_cast<const float4*>(&xs[(tm + 64) * LDX + kk]);
      double x0a = (double)xv0.x, x0b = (double)xv0.y,
             x0c = (double)xv0.z, x0d = (double)xv0.w;
      double x1a = (double)xv1.x, x1b = (double)xv1.y,
             x1c = (double)xv1.z, x1d = (double)xv1.w;
#pragma unroll
      for (int j = 0; j < 10; ++j) {
        const double* wr = &wlds[(nbu + j) * BK + kk];  // broadcast ds_read
        double wa = wr[0], wb = wr[1], wc = wr[2], wd = wr[3];
        acc[0][j] = fma(x0a, wa, acc[0][j]);
        acc[0][j] = fma(x0b, wb, acc[0][j]);
        acc[0][j] = fma(x0c, wc, acc[0][j]);
        acc[0][j] = fma(x0d, wd, acc[0][j]);
        acc[1][j] = fma(x1a, wa, acc[1][j]);
        acc[1][j] = fma(x1b, wb, acc[1][j]);
        acc[1][j] = fma(x1c, wc, acc[1][j]);
        acc[1][j] = fma(x1d, wd, acc[1][j]);
      }
    }
    __syncthreads();
  }

#pragma unroll
  for (int r = 0; r < 2; ++r) {
    const size_t mrow = (size_t)m0 + tm + r * 64;
#pragma unroll
    for (int j = 0; j < 10; ++j)
      cur[mrow * NOUT + nbu + j] = (float)acc[r][j];
  }
}

// One thread per (b, n) chain; 17 chunks of 15 t-steps, next chunk's cur
// loads prefetched before computing the current chunk (hides L2 latency).
// Per-step math identical to the validated scan (asm barrier blocks fma
// contraction of 0.95f*mem + cur, matching numpy's two roundings).
__global__ __launch_bounds__(64) void lif_scan_kernel(
    float* __restrict__ spk, float* __restrict__ curmem) {
  const int idx = blockIdx.x * 64 + threadIdx.x;  // 0..10239
  float mem = 0.f;
  float c[15];
#pragma unroll
  for (int i = 0; i < 15; ++i) c[i] = curmem[(size_t)i * BN_CH + idx];

  for (int ch = 0; ch < 17; ++ch) {
    const int t0 = ch * 15;
    float n[15];
    if (ch != 16) {
#pragma unroll
      for (int i = 0; i < 15; ++i)
        n[i] = curmem[(size_t)(t0 + 15 + i) * BN_CH + idx];
    }
    float m_[15], s_[15];
#pragma unroll
    for (int i = 0; i < 15; ++i) {
      float reset = (mem > 1.0f) ? 1.0f : 0.0f;
      float decay = 0.95f * mem;
      asm volatile("" : "+v"(decay));  // forbid fma contraction
      float summ = decay + c[i];
      float mnew = summ * (1.0f - reset);
      m_[i] = mnew;
      s_[i] = (mnew > 1.0f) ? 1.0f : 0.0f;
      mem = mnew;
    }
#pragma unroll
    for (int i = 0; i < 15; ++i) {
      curmem[(size_t)(t0 + i) * BN_CH + idx] = m_[i];
      spk[(size_t)(t0 + i) * BN_CH + idx] = s_[i];
    }
    if (ch != 16) {
#pragma unroll
      for (int i = 0; i < 15; ++i) c[i] = n[i];
    }
  }
}

extern "C" void kernel_launch(void* const* d_in, const int* in_sizes, int n_in,
                              void* d_out, int out_size, void* d_ws,
                              size_t ws_size, hipStream_t stream) {
  (void)in_sizes; (void)n_in; (void)out_size; (void)d_ws; (void)ws_size;
  const float* X = (const float*)d_in[0];
  const float* W = (const float*)d_in[1];
  float* out = (float*)d_out;
  float* spk = out;            // [255,256,40]
  float* memout = out + TBN;   // [255,256,40], used as cur scratch then mem
  double* Wd = (double*)out;   // 251 KB scratch at head of spk region

  wconv_kernel<<<(NOUT * NIN + 255) / 256, 256, 0, stream>>>(W, Wd);
  lif_gemm_kernel<<<MROWS / BM, 256, 0, stream>>>(X, Wd, memout);
  lif_scan_kernel<<<BN_CH / 64, 64, 0, stream>>>(spk, memout);
}

// Round 8
// 142.270 us; speedup vs baseline: 1.3358x; 1.1142x over previous
//
#include <hip/hip_runtime.h>
#include <hip/hip_bf16.h>

// Problem: T=255, B=256, NIN=784, NOUT=40
// out layout: [spk_rec (255*256*40) | mem_rec (255*256*40)] fp32
#define T_STEPS 255
#define BATCH 256
#define NIN 784
#define NOUT 40
#define MROWS (T_STEPS * BATCH)          // 65280
#define TBN (T_STEPS * BATCH * NOUT)     // 2611200
#define BN_CH (BATCH * NOUT)             // 10240

#define BM 128    // 4 rows/thread x 32 lane-rows -> grid 510
#define BK 56     // 784 = 14 * 56
#define LDX 60    // fp32 X LDS row stride (dwords), 16B-aligned rows
#define LDWC 60   // fp32 W LDS row stride (dwords)

// fp64-VALU GEMM, 4 rows x 5 cols per thread.
// Lanes: rl = lane&31 (row in 32-row band), h = lane>>5 (col half) ->
// X reads 2-way-aliased (free), W reads 2-address broadcast (free).
// FMA chain per output element is bit-identical to the validated round-2
// kernel (k ascending, quads of 4 sequential FMAs, fp64 cvt of fp32 data):
// cur is correctly-rounded fp32 -> spike decisions match the references.
__global__ __launch_bounds__(256) void lif_gemm_kernel(
    const float* __restrict__ X, const float* __restrict__ W,
    float* __restrict__ cur) {
  __shared__ float xs[BM * LDX];      // 30.0 KB
  __shared__ float wl[NOUT * LDWC];   // 9.6 KB
  const int tid = threadIdx.x;
  const int m0 = blockIdx.x * BM;
  const int w = tid >> 6;        // wave 0..3
  const int l = tid & 63;
  const int rl = l & 31;         // row within 32-row band
  const int h = l >> 5;          // col-half 0/1
  const int c0 = (w * 2 + h) * 5;  // col base: 8 groups of 5 -> 40 cols

  double acc[4][5];
#pragma unroll
  for (int r = 0; r < 4; ++r)
#pragma unroll
    for (int c = 0; c < 5; ++c) acc[r][c] = 0.0;

  for (int k0 = 0; k0 < NIN; k0 += BK) {
    // stage X tile: 128 rows x 56 cols fp32 = 1792 float4 / 256 thr = 7 each
#pragma unroll
    for (int i = 0; i < 7; ++i) {
      unsigned id = tid + i * 256u;
      unsigned row = id / 14u;  // 14 float4 per row
      unsigned c4 = id % 14u;
      float4 v = *reinterpret_cast<const float4*>(
          X + (size_t)(m0 + row) * NIN + k0 + c4 * 4);
      *reinterpret_cast<float4*>(&xs[row * LDX + c4 * 4]) = v;
    }
    // stage W tile: 40 rows x 56 cols fp32 = 560 float4
#pragma unroll
    for (int i = 0; i < 3; ++i) {
      unsigned id = tid + i * 256u;
      if (id < NOUT * 14u) {
        unsigned row = id / 14u;
        unsigned c4 = id % 14u;
        float4 v = *reinterpret_cast<const float4*>(
            W + (size_t)row * NIN + k0 + c4 * 4);
        *reinterpret_cast<float4*>(&wl[row * LDWC + c4 * 4]) = v;
      }
    }
    __syncthreads();

#pragma unroll
    for (int kk = 0; kk < BK; kk += 4) {
      double xd[4][4];
#pragma unroll
      for (int r = 0; r < 4; ++r) {
        float4 xv = *reinterpret_cast<const float4*>(
            &xs[(rl + 32 * r) * LDX + kk]);
        xd[r][0] = (double)xv.x; xd[r][1] = (double)xv.y;
        xd[r][2] = (double)xv.z; xd[r][3] = (double)xv.w;
      }
#pragma unroll
      for (int c = 0; c < 5; ++c) {
        float4 wv = *reinterpret_cast<const float4*>(
            &wl[(c0 + c) * LDWC + kk]);
        double wa = (double)wv.x, wb = (double)wv.y,
               wc = (double)wv.z, wd = (double)wv.w;
#pragma unroll
        for (int r = 0; r < 4; ++r) {
          acc[r][c] = fma(xd[r][0], wa, acc[r][c]);
          acc[r][c] = fma(xd[r][1], wb, acc[r][c]);
          acc[r][c] = fma(xd[r][2], wc, acc[r][c]);
          acc[r][c] = fma(xd[r][3], wd, acc[r][c]);
        }
      }
    }
    __syncthreads();
  }

#pragma unroll
  for (int r = 0; r < 4; ++r) {
    const size_t mrow = (size_t)m0 + rl + 32 * r;
#pragma unroll
    for (int c = 0; c < 5; ++c)
      cur[mrow * NOUT + c0 + c] = (float)acc[r][c];
  }
}

// One thread per (b, n) chain; 17 chunks of 15 t-steps, next chunk's cur
// loads prefetched before computing the current chunk (hides L2 latency).
// Per-step math identical to the validated scan (asm barrier blocks fma
// contraction of 0.95f*mem + cur, matching numpy's two roundings).
__global__ __launch_bounds__(64) void lif_scan_kernel(
    float* __restrict__ spk, float* __restrict__ curmem) {
  const int idx = blockIdx.x * 64 + threadIdx.x;  // 0..10239
  float mem = 0.f;
  float c[15];
#pragma unroll
  for (int i = 0; i < 15; ++i) c[i] = curmem[(size_t)i * BN_CH + idx];

  for (int ch = 0; ch < 17; ++ch) {
    const int t0 = ch * 15;
    float n[15];
    if (ch != 16) {
#pragma unroll
      for (int i = 0; i < 15; ++i)
        n[i] = curmem[(size_t)(t0 + 15 + i) * BN_CH + idx];
    }
    float m_[15], s_[15];
#pragma unroll
    for (int i = 0; i < 15; ++i) {
      float reset = (mem > 1.0f) ? 1.0f : 0.0f;
      float decay = 0.95f * mem;
      asm volatile("" : "+v"(decay));  // forbid fma contraction
      float summ = decay + c[i];
      float mnew = summ * (1.0f - reset);
      m_[i] = mnew;
      s_[i] = (mnew > 1.0f) ? 1.0f : 0.0f;
      mem = mnew;
    }
#pragma unroll
    for (int i = 0; i < 15; ++i) {
      curmem[(size_t)(t0 + i) * BN_CH + idx] = m_[i];
      spk[(size_t)(t0 + i) * BN_CH + idx] = s_[i];
    }
    if (ch != 16) {
#pragma unroll
      for (int i = 0; i < 15; ++i) c[i] = n[i];
    }
  }
}

extern "C" void kernel_launch(void* const* d_in, const int* in_sizes, int n_in,
                              void* d_out, int out_size, void* d_ws,
                              size_t ws_size, hipStream_t stream) {
  (void)in_sizes; (void)n_in; (void)out_size; (void)d_ws; (void)ws_size;
  const float* X = (const float*)d_in[0];
  const float* W = (const float*)d_in[1];
  float* out = (float*)d_out;
  float* spk = out;            // [255,256,40]
  float* memout = out + TBN;   // [255,256,40], used as cur scratch then mem

  lif_gemm_kernel<<<MROWS / BM, 256, 0, stream>>>(X, W, memout);
  lif_scan_kernel<<<BN_CH / 64, 64, 0, stream>>>(spk, memout);
}